// Round 10
// baseline (44.440 us; speedup 1.0000x reference)
//
#include <hip/hip_runtime.h>
#include <hip/hip_bf16.h>

// B=8, N=4096, L=256, E=64, D=128, Q4=32
#define B_ 8
#define N_ 4096
#define L_ 256
#define E_ 64
#define D_ 128

typedef const float* fp;
typedef __attribute__((ext_vector_type(8))) short short8;
typedef __attribute__((ext_vector_type(4))) float f32x4;

__device__ __forceinline__ short f2bf(float x) {
  __hip_bfloat16 h = __float2bfloat16(x);
  return __builtin_bit_cast(short, h);
}

// quaternion block tables: W[dout,q] block (br,bc) = sgn * Qsel[a*32+b]
__device__ __constant__ int   selT[16] = {0,1,2,3, 1,0,3,2, 2,3,0,1, 3,2,1,0};
__device__ __constant__ float sgnT[16] = {1.f,-1.f,-1.f,-1.f, 1.f,1.f,-1.f,1.f,
                                          1.f,1.f,1.f,-1.f, 1.f,-1.f,1.f,1.f};

// ws layout (floats):
//   [0,8192)        m0frag: 16384 ushorts, bf16 M0 in MFMA B-fragment order
//   [16384,32768)   M1 row-major
//   [32768,49152)   M2 row-major
//   [49152,49280)   c
//   [49280,73856)   qkv (q|k|v, each [64][128])
//   [73856,74368)   cnt
//   [74368,139904)  VG
//   [139904,402048) TG
//   [402048,410240) kT: k transposed [128][64]

// K1: blocks 0..95: M build (LDS-staged Q). 96..191: qkv (+kT). 192..199: hist.
__global__ __launch_bounds__(256) void k_setup(
    fp Pr_w, fp Pi_w, fp Pj_w, fp Pk_w,
    fp Pr_b, fp Pi_b, fp Pj_b, fp Pk_b,
    fp Qr, fp Qi, fp Qj, fp Qk, fp fusion_bias,
    fp var_he_w, fp Wq, fp bq, fp Wk, fp bk, fp Wv, fp bv,
    fp xmask, const int* vidx,
    float* ws) {
  int bid = blockIdx.x, tid = threadIdx.x;
  float* M = ws;
  unsigned short* m0frag = (unsigned short*)ws;
  float* c = ws + 49152;
  float* qkv = ws + 49280;
  float* cnt = ws + 73856;
  float* kT = ws + 402048;
  if (bid < 96) {
    __shared__ float qlds[4][32][33];   // +1 pad: a-stride 33 kills conflicts
    {
      fp Qsrc[4] = {Qr, Qi, Qj, Qk};
      for (int lid = tid; lid < 4096; lid += 256) {
        int mat = lid >> 10, el = lid & 1023;
        qlds[mat][el >> 5][el & 31] = Qsrc[mat][el];
      }
    }
    __syncthreads();
    int m = bid >> 5, di0 = (bid & 31) * 4;
    int sub = tid >> 7, dd = tid & 127;
    int br = dd >> 5, a = dd & 31;
    const float* w0 = qlds[br][a];                 // bc=0 row, sign +1
    int t1 = br * 4 + m + 1;
    const float* w1 = qlds[selT[t1]][a];
    float s1 = sgnT[t1];
    fp Pm = (m == 0) ? Pi_w : (m == 1) ? Pj_w : Pk_w;
#pragma unroll
    for (int ii = 0; ii < 2; ++ii) {
      int di = di0 + ii * 2 + sub;
      const float* pr = Pr_w + (m * 128 + di) * 32;
      const float* pm = Pm + di * 32;
      float acc = 0.f;
#pragma unroll
      for (int q = 0; q < 32; ++q)
        acc += pr[q] * w0[q] + s1 * pm[q] * w1[q];
      if (m == 0) {
        // bf16 fragment order: frag f=fn*4+ft, lane l=hi*16+(dd&15), elem j
        int fn = dd >> 4, ft = di >> 5, hi = (di >> 3) & 3, j = di & 7;
        int l = hi * 16 + (dd & 15);
        m0frag[((fn * 4 + ft) * 64 + l) * 8 + j] = (unsigned short)f2bf(acc);
      } else {
        M[m * 16384 + di * 128 + dd] = acc;       // M1, M2 row-major
      }
    }
    if (bid == 0 && tid < 128) {                   // c vector
      float acc = fusion_bias ? fusion_bias[tid] : 0.f;
#pragma unroll
      for (int bc = 0; bc < 4; ++bc) {
        fp Pb = (bc == 0) ? Pr_b : (bc == 1) ? Pi_b : (bc == 2) ? Pj_b : Pk_b;
        int t = br * 4 + bc;
        const float* wr = qlds[selT[t]][a];
        float sg = sgnT[t];
        float part = 0.f;
#pragma unroll
        for (int q = 0; q < 32; ++q) part += Pb[q] * wr[q];
        acc += sg * part;
      }
      c[tid] = acc;
    }
  } else if (bid < 192) {
    int id = (bid - 96) * 256 + tid;  // < 24576
    int which = id >> 13, rem = id & 8191, e = rem >> 7, d = rem & 127;
    fp W = (which == 0) ? Wq : (which == 1) ? Wk : Wv;
    fp bb = (which == 0) ? bq : (which == 1) ? bk : bv;
    float acc = bb[d];
    for (int d2 = 0; d2 < 128; ++d2)
      acc += fmaxf(var_he_w[e * 128 + d2], 0.f) * W[d2 * 128 + d];
    qkv[id] = acc;
    if (which == 1) kT[d * 64 + e] = acc;   // transposed copy for coalesced QK^T
  } else {
    __shared__ int hc[64];
    int b = bid - 192;  // < 8
    if (tid < 64) hc[tid] = 0;
    __syncthreads();
    for (int n = tid; n < N_; n += 256)
      if (xmask[b * N_ + n] != 0.f)
        atomicAdd(&hc[vidx[b * N_ + n] & 63], 1);
    __syncthreads();
    if (tid < 64) cnt[b * 64 + tid] = (float)hc[tid];
  }
}

// K2: blocks 0..127: VG, 4 e's per block (coalesced kT QK^T, shared M2).
//     blocks 128..383: TG, 8 rows per block (shared M1).
__global__ __launch_bounds__(128) void k_mid(
    fp thr_p, fp mc_p, fp mark, fp W_temp, fp b_temp,
    float* ws) {
  const float* M1 = ws + 16384;
  const float* M2 = ws + 32768;
  const float* qkv = ws + 49280;
  const float* cnt = ws + 73856;
  float* VG = ws + 74368;
  float* TG = ws + 139904;
  const float* kT = ws + 402048;
  int bid = blockIdx.x, t = threadIdx.x;
  if (bid < 128) {
    __shared__ float q4[4][128];
    __shared__ float attn4[4][64];
    __shared__ float va4[4][128];
    int b = bid >> 4, e0 = (bid & 15) << 2;
    const float* q = qkv;
    const float* v = qkv + 16384;
    for (int i = t; i < 512; i += 128)
      q4[i >> 7][i & 127] = q[(e0 + (i >> 7)) * 128 + (i & 127)];
    __syncthreads();
    int w = t >> 6, f = t & 63;
    float thv = thr_p ? thr_p[0] : 0.f;
    float mcv = mc_p ? mc_p[0] : 0.5f;
#pragma unroll
    for (int pass = 0; pass < 2; ++pass) {
      int ee = pass * 2 + w;
      int e = e0 + ee;
      float acc = 0.f;
      for (int d = 0; d < 128; ++d) acc += q4[ee][d] * kT[d * 64 + f];
      float s = acc * 0.08838834764831845f;
      if (f == e) {
        float aux = cnt[b * 64 + e] * (1.f / 64.f);
        if (aux != 0.f && s > thv) s = (1.f - mcv) * s + mcv * aux;
      }
      float m = s;
      for (int o = 32; o; o >>= 1) m = fmaxf(m, __shfl_xor(m, o));
      float ex = __expf(s - m);
      float sum = ex;
      for (int o = 32; o; o >>= 1) sum += __shfl_xor(sum, o);
      attn4[ee][f] = ex / sum;
    }
    __syncthreads();
    float a0 = 0.f, a1 = 0.f, a2 = 0.f, a3 = 0.f;
    for (int ff = 0; ff < 64; ++ff) {
      float vv = v[ff * 128 + t];
      a0 += attn4[0][ff] * vv;
      a1 += attn4[1][ff] * vv;
      a2 += attn4[2][ff] * vv;
      a3 += attn4[3][ff] * vv;
    }
    va4[0][t] = a0; va4[1][t] = a1; va4[2][t] = a2; va4[3][t] = a3;
    __syncthreads();
    float g0 = 0.f, g1 = 0.f, g2 = 0.f, g3 = 0.f;
    for (int di = 0; di < 128; ++di) {
      float m2v = M2[di * 128 + t];
      g0 += va4[0][di] * m2v;
      g1 += va4[1][di] * m2v;
      g2 += va4[2][di] * m2v;
      g3 += va4[3][di] * m2v;
    }
    float* vgb = VG + (b * 64 + e0) * 128 + t;
    vgb[0] = g0; vgb[128] = g1; vgb[256] = g2; vgb[384] = g3;
  } else {
    __shared__ float tb[8][128];
    int r0 = (bid - 128) * 8;  // flattened b*L+l row base
#pragma unroll
    for (int r = 0; r < 8; ++r)
      tb[r][t] = sinf(mark[r0 + r] * W_temp[t] + b_temp[t]);
    __syncthreads();
    float a[8];
#pragma unroll
    for (int r = 0; r < 8; ++r) a[r] = 0.f;
    for (int di = 0; di < 128; ++di) {
      float m1v = M1[di * 128 + t];
#pragma unroll
      for (int r = 0; r < 8; ++r) a[r] += tb[r][di] * m1v;
    }
#pragma unroll
    for (int r = 0; r < 8; ++r) TG[(r0 + r) * 128 + t] = a[r];
  }
}

// K3: MFMA main. Block = 64 nodes, 4 waves x 16 nodes. B-frags streamed
// from LDS inside the fn loop.
__global__ __launch_bounds__(256) void k_mainf(
    fp x_L, fp x_y_mask, fp y_mask_L, const int* vidx, const int* tidx,
    fp W_obs, fp b_obs, const float* ws, float* out) {
  __shared__ short8 m0s[2048];                // 32 KB: M0 frags, LDS-resident
  const short8* fr = (const short8*)ws;       // m0frag (fragment-ordered)
  const float* c = ws + 49152;
  const float* VG = ws + 74368;
  const float* TG = ws + 139904;
  int tid = threadIdx.x;
#pragma unroll
  for (int i = 0; i < 8; ++i) m0s[tid + i * 256] = fr[tid + i * 256];
  __syncthreads();

  int w = tid >> 6, l = tid & 63;
  int nb = blockIdx.x * 64 + w * 16;
  int b = blockIdx.x >> 6;

  int nodeA = nb + (l & 15);
  float mask = x_y_mask[nodeA];
  float xa = x_L[nodeA];
  float xb = 1.f - mask + y_mask_L[nodeA];
  short8 af[4];
#pragma unroll
  for (int ft = 0; ft < 4; ++ft) {
#pragma unroll
    for (int j = 0; j < 8; ++j) {
      int col = ft * 32 + ((l >> 4) << 3) + j;
      float o = fmaxf(xa * W_obs[col] + xb * W_obs[128 + col] + b_obs[col], 0.f) * mask;
      af[ft][j] = f2bf(o);
    }
  }

  f32x4 acc[8];
#pragma unroll
  for (int fn = 0; fn < 8; ++fn) acc[fn] = (f32x4)(0.f);
#pragma unroll
  for (int fn = 0; fn < 8; ++fn) {
#pragma unroll
    for (int ft = 0; ft < 4; ++ft) {
      short8 bf = m0s[(fn * 4 + ft) * 64 + l];
      acc[fn] = __builtin_amdgcn_mfma_f32_16x16x32_bf16(af[ft], bf, acc[fn], 0, 0, 0);
    }
  }

  int colbase = l & 15;
  float cv[8];
#pragma unroll
  for (int fn = 0; fn < 8; ++fn) cv[fn] = c[fn * 16 + colbase];
#pragma unroll
  for (int rg = 0; rg < 4; ++rg) {
    int node = nb + ((l >> 4) << 2) + rg;
    float m2 = x_y_mask[node];
    int ti = tidx[node] & 255, vi = vidx[node] & 63;
    const float* tgr = TG + (b * 256 + ti) * 128;
    const float* vgr = VG + (b * 64 + vi) * 128;
    float* orow = out + node * 128;
#pragma unroll
    for (int fn = 0; fn < 8; ++fn) {
      int col = fn * 16 + colbase;
      orow[col] = acc[fn][rg] + cv[fn] + m2 * (tgr[col] + vgr[col]);
    }
  }
}

extern "C" void kernel_launch(void* const* d_in, const int* in_sizes, int n_in,
                              void* d_out, int out_size, void* d_ws, size_t ws_size,
                              hipStream_t stream) {
  const void* P[33];
  {
    int p = 0;
    for (int i = 0; i < 33; ++i) {
      bool isopt = (i == 6 || i == 18 || i == 19);
      if (isopt) {
        if (p < n_in && in_sizes[p] == 1) P[i] = d_in[p++];
        else P[i] = nullptr;
      } else {
        P[i] = (p < n_in) ? d_in[p++] : nullptr;
      }
    }
  }
  fp x_L      = (fp)P[0];
  fp x_y_mask = (fp)P[1];
  fp y_mask_L = (fp)P[2];
  fp x_y_mark = (fp)P[3];
  const int* vidx = (const int*)P[4];
  const int* tidx = (const int*)P[5];
  fp W_obs = (fp)P[7];
  fp b_obs = (fp)P[8];
  fp W_temp = (fp)P[9];
  fp b_temp = (fp)P[10];
  fp var_he_w = (fp)P[11];
  fp Wq = (fp)P[12]; fp bq = (fp)P[13];
  fp Wk = (fp)P[14]; fp bk = (fp)P[15];
  fp Wv = (fp)P[16]; fp bv = (fp)P[17];
  fp thr = (fp)P[18]; fp mc = (fp)P[19];
  fp Pr_w = (fp)P[20]; fp Pr_b = (fp)P[21];
  fp Pi_w = (fp)P[22]; fp Pi_b = (fp)P[23];
  fp Pj_w = (fp)P[24]; fp Pj_b = (fp)P[25];
  fp Pk_w = (fp)P[26]; fp Pk_b = (fp)P[27];
  fp Qr = (fp)P[28]; fp Qi = (fp)P[29];
  fp Qj = (fp)P[30]; fp Qk = (fp)P[31];
  fp fusion_bias = (fp)P[32];

  float* ws = (float*)d_ws;

  hipLaunchKernelGGL(k_setup, dim3(200), dim3(256), 0, stream,
                     Pr_w, Pi_w, Pj_w, Pk_w, Pr_b, Pi_b, Pj_b, Pk_b,
                     Qr, Qi, Qj, Qk, fusion_bias,
                     var_he_w, Wq, bq, Wk, bk, Wv, bv,
                     x_y_mask, vidx, ws);
  hipLaunchKernelGGL(k_mid, dim3(384), dim3(128), 0, stream,
                     thr, mc, x_y_mark, W_temp, b_temp, ws);
  hipLaunchKernelGGL(k_mainf, dim3(512), dim3(256), 0, stream,
                     x_L, x_y_mask, y_mask_L, vidx, tidx, W_obs, b_obs,
                     ws, (float*)d_out);
}

// Round 11
// 43.217 us; speedup vs baseline: 1.0283x; 1.0283x over previous
//
#include <hip/hip_runtime.h>
#include <hip/hip_bf16.h>

// B=8, N=4096, L=256, E=64, D=128, Q4=32
#define B_ 8
#define N_ 4096
#define L_ 256
#define E_ 64
#define D_ 128

typedef const float* fp;
typedef __attribute__((ext_vector_type(8))) short short8;
typedef __attribute__((ext_vector_type(4))) float f32x4;

__device__ __forceinline__ short f2bf(float x) {
  __hip_bfloat16 h = __float2bfloat16(x);
  return __builtin_bit_cast(short, h);
}

// quaternion block tables: W[dout,q] block (br,bc) = sgn * Qsel[a*32+b]
__device__ __constant__ int   selT[16] = {0,1,2,3, 1,0,3,2, 2,3,0,1, 3,2,1,0};
__device__ __constant__ float sgnT[16] = {1.f,-1.f,-1.f,-1.f, 1.f,1.f,-1.f,1.f,
                                          1.f,1.f,1.f,-1.f, 1.f,-1.f,1.f,1.f};

// ws layout (floats):
//   [0,8192)        m0frag: 16384 ushorts, bf16 M0 in MFMA B-fragment order
//   [16384,32768)   M1 row-major
//   [32768,49152)   M2 row-major
//   [49152,49280)   c
//   [49280,73856)   qkv (q|k|v, each [64][128])
//   [73856,74368)   cnt
//   [74368,139904)  VG
//   [139904,402048) TG
//   [402048,410240) kT: k transposed [128][64]

// K1: blocks 0..95: M build (LDS-staged Q). 96..191: qkv (+kT). 192..199: hist.
__global__ __launch_bounds__(256) void k_setup(
    fp Pr_w, fp Pi_w, fp Pj_w, fp Pk_w,
    fp Pr_b, fp Pi_b, fp Pj_b, fp Pk_b,
    fp Qr, fp Qi, fp Qj, fp Qk, fp fusion_bias,
    fp var_he_w, fp Wq, fp bq, fp Wk, fp bk, fp Wv, fp bv,
    fp xmask, const int* vidx,
    float* ws) {
  int bid = blockIdx.x, tid = threadIdx.x;
  float* M = ws;
  unsigned short* m0frag = (unsigned short*)ws;
  float* c = ws + 49152;
  float* qkv = ws + 49280;
  float* cnt = ws + 73856;
  float* kT = ws + 402048;
  if (bid < 96) {
    __shared__ float qlds[4][32][33];   // +1 pad: a-stride 33 kills conflicts
    {
      fp Qsrc[4] = {Qr, Qi, Qj, Qk};
      for (int lid = tid; lid < 4096; lid += 256) {
        int mat = lid >> 10, el = lid & 1023;
        qlds[mat][el >> 5][el & 31] = Qsrc[mat][el];
      }
    }
    __syncthreads();
    int m = bid >> 5, di0 = (bid & 31) * 4;
    int sub = tid >> 7, dd = tid & 127;
    int br = dd >> 5, a = dd & 31;
    const float* w0 = qlds[br][a];                 // bc=0 row, sign +1
    int t1 = br * 4 + m + 1;
    const float* w1 = qlds[selT[t1]][a];
    float s1 = sgnT[t1];
    fp Pm = (m == 0) ? Pi_w : (m == 1) ? Pj_w : Pk_w;
#pragma unroll
    for (int ii = 0; ii < 2; ++ii) {
      int di = di0 + ii * 2 + sub;
      const float* pr = Pr_w + (m * 128 + di) * 32;
      const float* pm = Pm + di * 32;
      float acc = 0.f;
#pragma unroll
      for (int q = 0; q < 32; ++q)
        acc += pr[q] * w0[q] + s1 * pm[q] * w1[q];
      if (m == 0) {
        // bf16 fragment order: frag f=fn*4+ft, lane l=hi*16+(dd&15), elem j
        int fn = dd >> 4, ft = di >> 5, hi = (di >> 3) & 3, j = di & 7;
        int l = hi * 16 + (dd & 15);
        m0frag[((fn * 4 + ft) * 64 + l) * 8 + j] = (unsigned short)f2bf(acc);
      } else {
        M[m * 16384 + di * 128 + dd] = acc;       // M1, M2 row-major
      }
    }
    if (bid == 0 && tid < 128) {                   // c vector
      float acc = fusion_bias ? fusion_bias[tid] : 0.f;
#pragma unroll
      for (int bc = 0; bc < 4; ++bc) {
        fp Pb = (bc == 0) ? Pr_b : (bc == 1) ? Pi_b : (bc == 2) ? Pj_b : Pk_b;
        int t = br * 4 + bc;
        const float* wr = qlds[selT[t]][a];
        float sg = sgnT[t];
        float part = 0.f;
#pragma unroll
        for (int q = 0; q < 32; ++q) part += Pb[q] * wr[q];
        acc += sg * part;
      }
      c[tid] = acc;
    }
  } else if (bid < 192) {
    int id = (bid - 96) * 256 + tid;  // < 24576
    int which = id >> 13, rem = id & 8191, e = rem >> 7, d = rem & 127;
    fp W = (which == 0) ? Wq : (which == 1) ? Wk : Wv;
    fp bb = (which == 0) ? bq : (which == 1) ? bk : bv;
    float acc = bb[d];
    for (int d2 = 0; d2 < 128; ++d2)
      acc += fmaxf(var_he_w[e * 128 + d2], 0.f) * W[d2 * 128 + d];
    qkv[id] = acc;
    if (which == 1) kT[d * 64 + e] = acc;   // transposed copy for coalesced QK^T
  } else {
    __shared__ int hc[64];
    int b = bid - 192;  // < 8
    if (tid < 64) hc[tid] = 0;
    __syncthreads();
    for (int n = tid; n < N_; n += 256)
      if (xmask[b * N_ + n] != 0.f)
        atomicAdd(&hc[vidx[b * N_ + n] & 63], 1);
    __syncthreads();
    if (tid < 64) cnt[b * 64 + tid] = (float)hc[tid];
  }
}

// K2: blocks 0..127: VG, 4 e's per block (coalesced kT QK^T, shared M2).
//     blocks 128..639: TG, 4 rows per block (shared M1, higher occupancy).
__global__ __launch_bounds__(128) void k_mid(
    fp thr_p, fp mc_p, fp mark, fp W_temp, fp b_temp,
    float* ws) {
  const float* M1 = ws + 16384;
  const float* M2 = ws + 32768;
  const float* qkv = ws + 49280;
  const float* cnt = ws + 73856;
  float* VG = ws + 74368;
  float* TG = ws + 139904;
  const float* kT = ws + 402048;
  int bid = blockIdx.x, t = threadIdx.x;
  if (bid < 128) {
    __shared__ float q4[4][128];
    __shared__ float attn4[4][64];
    __shared__ float va4[4][128];
    int b = bid >> 4, e0 = (bid & 15) << 2;
    const float* q = qkv;
    const float* v = qkv + 16384;
    for (int i = t; i < 512; i += 128)
      q4[i >> 7][i & 127] = q[(e0 + (i >> 7)) * 128 + (i & 127)];
    __syncthreads();
    int w = t >> 6, f = t & 63;
    float thv = thr_p ? thr_p[0] : 0.f;
    float mcv = mc_p ? mc_p[0] : 0.5f;
#pragma unroll
    for (int pass = 0; pass < 2; ++pass) {
      int ee = pass * 2 + w;
      int e = e0 + ee;
      float acc = 0.f;
      for (int d = 0; d < 128; ++d) acc += q4[ee][d] * kT[d * 64 + f];
      float s = acc * 0.08838834764831845f;
      if (f == e) {
        float aux = cnt[b * 64 + e] * (1.f / 64.f);
        if (aux != 0.f && s > thv) s = (1.f - mcv) * s + mcv * aux;
      }
      float m = s;
      for (int o = 32; o; o >>= 1) m = fmaxf(m, __shfl_xor(m, o));
      float ex = __expf(s - m);
      float sum = ex;
      for (int o = 32; o; o >>= 1) sum += __shfl_xor(sum, o);
      attn4[ee][f] = ex / sum;
    }
    __syncthreads();
    float a0 = 0.f, a1 = 0.f, a2 = 0.f, a3 = 0.f;
    for (int ff = 0; ff < 64; ++ff) {
      float vv = v[ff * 128 + t];
      a0 += attn4[0][ff] * vv;
      a1 += attn4[1][ff] * vv;
      a2 += attn4[2][ff] * vv;
      a3 += attn4[3][ff] * vv;
    }
    va4[0][t] = a0; va4[1][t] = a1; va4[2][t] = a2; va4[3][t] = a3;
    __syncthreads();
    float g0 = 0.f, g1 = 0.f, g2 = 0.f, g3 = 0.f;
    for (int di = 0; di < 128; ++di) {
      float m2v = M2[di * 128 + t];
      g0 += va4[0][di] * m2v;
      g1 += va4[1][di] * m2v;
      g2 += va4[2][di] * m2v;
      g3 += va4[3][di] * m2v;
    }
    float* vgb = VG + (b * 64 + e0) * 128 + t;
    vgb[0] = g0; vgb[128] = g1; vgb[256] = g2; vgb[384] = g3;
  } else {
    __shared__ float tb[4][128];
    int r0 = (bid - 128) * 4;  // flattened b*L+l row base
#pragma unroll
    for (int r = 0; r < 4; ++r)
      tb[r][t] = sinf(mark[r0 + r] * W_temp[t] + b_temp[t]);
    __syncthreads();
    float a0 = 0.f, a1 = 0.f, a2 = 0.f, a3 = 0.f;
    for (int di = 0; di < 128; ++di) {
      float m1v = M1[di * 128 + t];
      a0 += tb[0][di] * m1v;
      a1 += tb[1][di] * m1v;
      a2 += tb[2][di] * m1v;
      a3 += tb[3][di] * m1v;
    }
    TG[(r0 + 0) * 128 + t] = a0;
    TG[(r0 + 1) * 128 + t] = a1;
    TG[(r0 + 2) * 128 + t] = a2;
    TG[(r0 + 3) * 128 + t] = a3;
  }
}

// K3: MFMA main. Block = 64 nodes, 4 waves x 16 nodes. B-frags streamed
// from LDS inside the fn loop.
__global__ __launch_bounds__(256) void k_mainf(
    fp x_L, fp x_y_mask, fp y_mask_L, const int* vidx, const int* tidx,
    fp W_obs, fp b_obs, const float* ws, float* out) {
  __shared__ short8 m0s[2048];                // 32 KB: M0 frags, LDS-resident
  const short8* fr = (const short8*)ws;       // m0frag (fragment-ordered)
  const float* c = ws + 49152;
  const float* VG = ws + 74368;
  const float* TG = ws + 139904;
  int tid = threadIdx.x;
#pragma unroll
  for (int i = 0; i < 8; ++i) m0s[tid + i * 256] = fr[tid + i * 256];
  __syncthreads();

  int w = tid >> 6, l = tid & 63;
  int nb = blockIdx.x * 64 + w * 16;
  int b = blockIdx.x >> 6;

  int nodeA = nb + (l & 15);
  float mask = x_y_mask[nodeA];
  float xa = x_L[nodeA];
  float xb = 1.f - mask + y_mask_L[nodeA];
  short8 af[4];
#pragma unroll
  for (int ft = 0; ft < 4; ++ft) {
#pragma unroll
    for (int j = 0; j < 8; ++j) {
      int col = ft * 32 + ((l >> 4) << 3) + j;
      float o = fmaxf(xa * W_obs[col] + xb * W_obs[128 + col] + b_obs[col], 0.f) * mask;
      af[ft][j] = f2bf(o);
    }
  }

  f32x4 acc[8];
#pragma unroll
  for (int fn = 0; fn < 8; ++fn) acc[fn] = (f32x4)(0.f);
#pragma unroll
  for (int fn = 0; fn < 8; ++fn) {
#pragma unroll
    for (int ft = 0; ft < 4; ++ft) {
      short8 bf = m0s[(fn * 4 + ft) * 64 + l];
      acc[fn] = __builtin_amdgcn_mfma_f32_16x16x32_bf16(af[ft], bf, acc[fn], 0, 0, 0);
    }
  }

  int colbase = l & 15;
  float cv[8];
#pragma unroll
  for (int fn = 0; fn < 8; ++fn) cv[fn] = c[fn * 16 + colbase];
#pragma unroll
  for (int rg = 0; rg < 4; ++rg) {
    int node = nb + ((l >> 4) << 2) + rg;
    float m2 = x_y_mask[node];
    int ti = tidx[node] & 255, vi = vidx[node] & 63;
    const float* tgr = TG + (b * 256 + ti) * 128;
    const float* vgr = VG + (b * 64 + vi) * 128;
    float* orow = out + node * 128;
#pragma unroll
    for (int fn = 0; fn < 8; ++fn) {
      int col = fn * 16 + colbase;
      orow[col] = acc[fn][rg] + cv[fn] + m2 * (tgr[col] + vgr[col]);
    }
  }
}

extern "C" void kernel_launch(void* const* d_in, const int* in_sizes, int n_in,
                              void* d_out, int out_size, void* d_ws, size_t ws_size,
                              hipStream_t stream) {
  const void* P[33];
  {
    int p = 0;
    for (int i = 0; i < 33; ++i) {
      bool isopt = (i == 6 || i == 18 || i == 19);
      if (isopt) {
        if (p < n_in && in_sizes[p] == 1) P[i] = d_in[p++];
        else P[i] = nullptr;
      } else {
        P[i] = (p < n_in) ? d_in[p++] : nullptr;
      }
    }
  }
  fp x_L      = (fp)P[0];
  fp x_y_mask = (fp)P[1];
  fp y_mask_L = (fp)P[2];
  fp x_y_mark = (fp)P[3];
  const int* vidx = (const int*)P[4];
  const int* tidx = (const int*)P[5];
  fp W_obs = (fp)P[7];
  fp b_obs = (fp)P[8];
  fp W_temp = (fp)P[9];
  fp b_temp = (fp)P[10];
  fp var_he_w = (fp)P[11];
  fp Wq = (fp)P[12]; fp bq = (fp)P[13];
  fp Wk = (fp)P[14]; fp bk = (fp)P[15];
  fp Wv = (fp)P[16]; fp bv = (fp)P[17];
  fp thr = (fp)P[18]; fp mc = (fp)P[19];
  fp Pr_w = (fp)P[20]; fp Pr_b = (fp)P[21];
  fp Pi_w = (fp)P[22]; fp Pi_b = (fp)P[23];
  fp Pj_w = (fp)P[24]; fp Pj_b = (fp)P[25];
  fp Pk_w = (fp)P[26]; fp Pk_b = (fp)P[27];
  fp Qr = (fp)P[28]; fp Qi = (fp)P[29];
  fp Qj = (fp)P[30]; fp Qk = (fp)P[31];
  fp fusion_bias = (fp)P[32];

  float* ws = (float*)d_ws;

  hipLaunchKernelGGL(k_setup, dim3(200), dim3(256), 0, stream,
                     Pr_w, Pi_w, Pj_w, Pk_w, Pr_b, Pi_b, Pj_b, Pk_b,
                     Qr, Qi, Qj, Qk, fusion_bias,
                     var_he_w, Wq, bq, Wk, bk, Wv, bv,
                     x_y_mask, vidx, ws);
  hipLaunchKernelGGL(k_mid, dim3(640), dim3(128), 0, stream,
                     thr, mc, x_y_mark, W_temp, b_temp, ws);
  hipLaunchKernelGGL(k_mainf, dim3(512), dim3(256), 0, stream,
                     x_L, x_y_mask, y_mask_L, vidx, tidx, W_obs, b_obs,
                     ws, (float*)d_out);
}